// Round 15
// baseline (233.340 us; speedup 1.0000x reference)
//
#include <hip/hip_runtime.h>

// GraphConstruction: x[1,1024,1024] fp32 -> A[4096,4096] in {0,1} fp32.
// patches[n,r,k] = x[h,w], h = (n&15)*64 + (r>>2)*16 + (n>>8),
//                          w = (r&3)*256 + k*16 + ((n>>4)&15)
// LOCKED NUMERICS (R6..R14, absmax 0):
//   sq[n,k]: acc = p0^2; acc = acc + fl(p_r^2), r ascending (plain adds)
//   G: acc = fmaf(a_r, b_r, acc), r ascending (fmaf(a,b,0)=fl(ab)=numpy 0+ab)
//   d2 = fmaf(-2,G,fl(si+sj));  all_k (d2 <= 49.0f);  A symmetric -> mirror.
// R15: R14 proved the DS pipe is the binding resource (pk_fma halved VALU,
//   dur flat). Move operand reads to the VMEM/L1 path: pre-transpose to
//   P2[k][r][n] in ws; adjacency kernel has NO LDS and NO barriers — per
//   (k,r) one dwordx4 a-read (wave: 4 distinct lines, 16-lane merge) + one
//   dwordx4 b-read (4 lines). L2 demand 266 MB ~ 8us aggregate. VGPR ~50 ->
//   ~32 waves/CU latency hiding. ws guarded: falls back to R13 kernel.

#define NPATCH 4096
#define BT 64

// ============================ R15 path ============================

__global__ __launch_bounds__(256) void transpose_kernel(const float* __restrict__ x,
                                                        float* __restrict__ P2) {
    int gid = blockIdx.x * 256 + threadIdx.x;   // 262144
    int nl = gid & 15;
    int c  = (gid >> 4) & 3;
    int n8 = (gid >> 6) & 15;
    int r  = (gid >> 10) & 15;
    int k  = gid >> 14;
    // x float4: elements j=0..3 are patches n = (n8<<8)|((4c+j)<<4)|nl at (r,k)
    int h = nl * 64 + (r >> 2) * 16 + n8;
    int w0 = (r & 3) * 256 + k * 16 + 4 * c;
    float4 v = *(const float4*)&x[h * 1024 + w0];
    const float* vp = (const float*)&v;
    float* dst = P2 + (((k * 16 + r) << 12) | (n8 << 8) | nl);
#pragma unroll
    for (int j = 0; j < 4; ++j)
        dst[(4 * c + j) << 4] = vp[j];
}

__global__ __launch_bounds__(256) void sq2_kernel(const float* __restrict__ P2,
                                                  float* __restrict__ sq) {
#pragma clang fp contract(off)
    int gid = blockIdx.x * 256 + threadIdx.x;   // 65536
    int n = gid & 4095;
    int k = gid >> 12;
    const float* p = P2 + ((k * 16) << 12) + n;
    float v0 = p[0];
    float acc = v0 * v0;
#pragma unroll
    for (int r = 1; r < 16; ++r) {
        float v = p[r << 12];
        float t = v * v;
        acc = acc + t;
    }
    sq[(k << 12) + n] = acc;
}

__global__ __launch_bounds__(256, 4) void adj2_kernel(const float* __restrict__ P2,
                                                      const float* __restrict__ sq,
                                                      float* __restrict__ A) {
#pragma clang fp contract(off)
    // linear -> lower-triangle (bi >= bj)
    int t = blockIdx.x;
    int bi = (int)((sqrtf(8.0f * (float)t + 1.0f) - 1.0f) * 0.5f);
    while ((bi + 1) * (bi + 2) / 2 <= t) ++bi;
    while (bi * (bi + 1) / 2 > t) --bi;
    int bj = t - bi * (bi + 1) / 2;

    const int i0 = bi * BT;
    const int j0 = bj * BT;
    const int tid = threadIdx.x;
    const int tx = tid & 15;       // j-cols tx*4..+3
    const int ty = tid >> 4;       // i-rows ty*4..+3
    const int ia = i0 + 4 * ty;
    const int ja = j0 + 4 * tx;

    unsigned int bad = 0u;         // bit u*4+v => some d2 > 49

    for (int k = 0; k < 16; ++k) {
        const float* base = P2 + (k << 16);
        float d[4][4];
#pragma unroll
        for (int u = 0; u < 4; ++u)
#pragma unroll
            for (int v = 0; v < 4; ++v) d[u][v] = 0.0f;
#pragma unroll
        for (int r = 0; r < 16; ++r) {
            float4 a4 = *(const float4*)&base[(r << 12) + ia];
            float4 b4 = *(const float4*)&base[(r << 12) + ja];
            const float* ap = (const float*)&a4;
            const float* bp = (const float*)&b4;
#pragma unroll
            for (int u = 0; u < 4; ++u)
#pragma unroll
                for (int v = 0; v < 4; ++v)
                    d[u][v] = fmaf(ap[u], bp[v], d[u][v]);
        }
        float4 si4 = *(const float4*)&sq[(k << 12) + ia];
        float4 sj4 = *(const float4*)&sq[(k << 12) + ja];
        const float* sip = (const float*)&si4;
        const float* sjp = (const float*)&sj4;
#pragma unroll
        for (int u = 0; u < 4; ++u)
#pragma unroll
            for (int v = 0; v < 4; ++v) {
                float s = sip[u] + sjp[v];            // fl(si+sj)
                float d2 = fmaf(-2.0f, d[u][v], s);   // fl(s-2G)
                bad |= (d2 > 49.0f) ? (1u << (u * 4 + v)) : 0u;
            }
    }

    // ---- stores: direct + mirrored (A exactly symmetric) ----
#pragma unroll
    for (int u = 0; u < 4; ++u) {
        float4 o;
        o.x = (bad >> (u * 4 + 0)) & 1u ? 0.0f : 1.0f;
        o.y = (bad >> (u * 4 + 1)) & 1u ? 0.0f : 1.0f;
        o.z = (bad >> (u * 4 + 2)) & 1u ? 0.0f : 1.0f;
        o.w = (bad >> (u * 4 + 3)) & 1u ? 0.0f : 1.0f;
        *(float4*)&A[(size_t)(i0 + ty * 4 + u) * NPATCH + j0 + tx * 4] = o;
    }
    if (bi != bj) {
#pragma unroll
        for (int v = 0; v < 4; ++v) {
            float4 o;
            o.x = (bad >> (0 * 4 + v)) & 1u ? 0.0f : 1.0f;
            o.y = (bad >> (1 * 4 + v)) & 1u ? 0.0f : 1.0f;
            o.z = (bad >> (2 * 4 + v)) & 1u ? 0.0f : 1.0f;
            o.w = (bad >> (3 * 4 + v)) & 1u ? 0.0f : 1.0f;
            *(float4*)&A[(size_t)(j0 + tx * 4 + v) * NPATCH + i0 + ty * 4] = o;
        }
    }
}

// ====================== R13 fallback (proven) ======================

#define KC 2
#define NPH 8
#define RSTRIDE 9

__device__ __forceinline__ int swzrow(int row) {
    return ((row >> 2) + (row >> 5)) & 7;
}

__global__ __launch_bounds__(256, 3) void adj_kernel(const float* __restrict__ x,
                                                     float* __restrict__ A) {
#pragma clang fp contract(off)
    __shared__ float4 Si[BT * RSTRIDE];
    __shared__ float4 Sj[BT * RSTRIDE];
    __shared__ float sqs[2][KC][BT];

    int t = blockIdx.x;
    int bi = (int)((sqrtf(8.0f * (float)t + 1.0f) - 1.0f) * 0.5f);
    while ((bi + 1) * (bi + 2) / 2 <= t) ++bi;
    while (bi * (bi + 1) / 2 > t) --bi;
    int bj = t - bi * (bi + 1) / 2;

    const int i0 = bi * BT;
    const int j0 = bj * BT;
    const int tid = threadIdx.x;
    const int tx = tid & 15;
    const int ty = tid >> 4;
    const int swzA = (ty + (ty >> 3)) & 7;
    const int swzB = (tx + (tx >> 3)) & 7;

    float m[4][4];
#pragma unroll
    for (int u = 0; u < 4; ++u)
#pragma unroll
        for (int v = 0; v < 4; ++v) m[u][v] = -3.0e38f;

    for (int kp = 0; kp < NPH; ++kp) {
        __syncthreads();
#pragma unroll
        for (int l = 0; l < 4; ++l) {
            int gid = l * 256 + tid;
            int side = gid >> 9;
            int q = gid & 511;
            int kl = q & 1;
            int r = (q >> 1) & 15;
            int rl = q >> 5;
            int k = kp * KC + kl;
            int b = side ? bj : bi;
            int h = rl * 64 + (r >> 2) * 16 + (b >> 2);
            int w0 = (r & 3) * 256 + k * 16 + ((4 * b) & 15);
            float4 v = *(const float4*)&x[h * 1024 + w0];
            const float* vp = (const float*)&v;
            int c = (kl << 2) | (r >> 2);
            int e = r & 3;
            float* Sb = side ? (float*)Sj : (float*)Si;
#pragma unroll
            for (int dd = 0; dd < 4; ++dd) {
                int row = 16 * dd + rl;
                int ch = c ^ swzrow(row);
                Sb[(row * RSTRIDE + ch) * 4 + e] = vp[dd];
            }
        }
        __syncthreads();
        {
            int side = tid >> 7;
            int kl = (tid >> 6) & 1;
            int row = tid & 63;
            const float4* Sb = (side ? Sj : Si) + row * RSTRIDE;
            int swz = swzrow(row);
            float acc;
            {
                float4 v = Sb[(kl * 4) ^ swz];
                acc = v.x * v.x;
                float t1 = v.y * v.y; acc = acc + t1;
                float t2 = v.z * v.z; acc = acc + t2;
                float t3 = v.w * v.w; acc = acc + t3;
            }
#pragma unroll
            for (int rc = 1; rc < 4; ++rc) {
                float4 v = Sb[(kl * 4 + rc) ^ swz];
                float t0 = v.x * v.x; acc = acc + t0;
                float t1 = v.y * v.y; acc = acc + t1;
                float t2 = v.z * v.z; acc = acc + t2;
                float t3 = v.w * v.w; acc = acc + t3;
            }
            sqs[side][kl][row] = acc;
        }
        __syncthreads();
#pragma unroll
        for (int kl = 0; kl < KC; ++kl) {
            float d[4][4];
#pragma unroll
            for (int u = 0; u < 4; ++u)
#pragma unroll
                for (int v = 0; v < 4; ++v) d[u][v] = 0.0f;
#pragma unroll
            for (int rc = 0; rc < 4; ++rc) {
                int c = kl * 4 + rc;
                float4 a[4], b[4];
#pragma unroll
                for (int u = 0; u < 4; ++u)
                    a[u] = Si[(ty * 4 + u) * RSTRIDE + (c ^ swzA)];
#pragma unroll
                for (int v = 0; v < 4; ++v)
                    b[v] = Sj[(tx * 4 + v) * RSTRIDE + (c ^ swzB)];
#pragma unroll
                for (int u = 0; u < 4; ++u)
#pragma unroll
                    for (int v = 0; v < 4; ++v) {
                        d[u][v] = fmaf(a[u].x, b[v].x, d[u][v]);
                        d[u][v] = fmaf(a[u].y, b[v].y, d[u][v]);
                        d[u][v] = fmaf(a[u].z, b[v].z, d[u][v]);
                        d[u][v] = fmaf(a[u].w, b[v].w, d[u][v]);
                    }
            }
            float4 si4 = *(const float4*)&sqs[0][kl][ty * 4];
            float4 sj4 = *(const float4*)&sqs[1][kl][tx * 4];
            const float* sip = (const float*)&si4;
            const float* sjp = (const float*)&sj4;
#pragma unroll
            for (int u = 0; u < 4; ++u)
#pragma unroll
                for (int v = 0; v < 4; ++v) {
                    float s = sip[u] + sjp[v];
                    float d2 = fmaf(-2.0f, d[u][v], s);
                    m[u][v] = fmaxf(m[u][v], d2);
                }
        }
    }

#pragma unroll
    for (int u = 0; u < 4; ++u) {
        float4 o;
        o.x = (m[u][0] <= 49.0f) ? 1.0f : 0.0f;
        o.y = (m[u][1] <= 49.0f) ? 1.0f : 0.0f;
        o.z = (m[u][2] <= 49.0f) ? 1.0f : 0.0f;
        o.w = (m[u][3] <= 49.0f) ? 1.0f : 0.0f;
        *(float4*)&A[(size_t)(i0 + ty * 4 + u) * NPATCH + j0 + tx * 4] = o;
    }
    if (bi != bj) {
#pragma unroll
        for (int v = 0; v < 4; ++v) {
            float4 o;
            o.x = (m[0][v] <= 49.0f) ? 1.0f : 0.0f;
            o.y = (m[1][v] <= 49.0f) ? 1.0f : 0.0f;
            o.z = (m[2][v] <= 49.0f) ? 1.0f : 0.0f;
            o.w = (m[3][v] <= 49.0f) ? 1.0f : 0.0f;
            *(float4*)&A[(size_t)(j0 + tx * 4 + v) * NPATCH + i0 + ty * 4] = o;
        }
    }
}

extern "C" void kernel_launch(void* const* d_in, const int* in_sizes, int n_in,
                              void* d_out, int out_size, void* d_ws, size_t ws_size,
                              hipStream_t stream) {
    const float* x = (const float*)d_in[0];
    float* A = (float*)d_out;

    const int nblk = (NPATCH / BT) * (NPATCH / BT + 1) / 2;  // 2080
    const size_t need = (size_t)4 * 1024 * 1024 + 256 * 1024;

    if (ws_size >= need) {
        float* P2 = (float*)d_ws;                                  // 4 MB
        float* sq = (float*)((char*)d_ws + (size_t)4 * 1024 * 1024); // 256 KB
        transpose_kernel<<<1024, 256, 0, stream>>>(x, P2);
        sq2_kernel<<<256, 256, 0, stream>>>(P2, sq);
        adj2_kernel<<<nblk, 256, 0, stream>>>(P2, sq, A);
    } else {
        adj_kernel<<<nblk, 256, 0, stream>>>(x, A);
    }
}

// Round 16
// 217.849 us; speedup vs baseline: 1.0711x; 1.0711x over previous
//
#include <hip/hip_runtime.h>

// GraphConstruction: x[1,1024,1024] fp32 -> A[4096,4096] in {0,1} fp32.
// patches[n,r,k] = x[h,w], h = (n&15)*64 + (r>>2)*16 + (n>>8),
//                          w = (r&3)*256 + k*16 + ((n>>4)&15)
// LOCKED NUMERICS (R6..R15, absmax 0):
//   sq[n,k]: acc = p0^2; acc = acc + fl(p_r^2), r ascending (plain adds)
//   G: acc = fmaf(a_r, b_r, acc), r ascending
//   d2 = fmaf(-2,G,fl(si+sj));  all_k (d2 <= 49.0f);  A symmetric -> mirror.
// R16 hybrid: R13 is DS-pipe-bound (~117us DS work); R15 all-VMEM was
//   latency-bound (VGPR 36 -> no loads in flight). Split streams: b-operands
//   from LDS (the 16-distinct-address side), a-operands via VMEM from P2 —
//   one 64B line per wave-instr (4 distinct 16B, 16-lane merge). DS traffic
//   halves; staging (j-only, from P2) loses the x-gather bit-munging VALU.
//   launch_bounds(256,2) so the allocator can batch a-loads (R15 lesson).
//   Staging swizzle c^(kr&7): writes uniform (8 lanes/bank-group = b128
//   floor), reads 2-way free. Numerics bit-identical, only operand sources.

#define NPATCH 4096
#define BT 64

// ---- P2[k][r][n] transpose (verified R15) ----
__global__ __launch_bounds__(256) void transpose_kernel(const float* __restrict__ x,
                                                        float* __restrict__ P2) {
    int gid = blockIdx.x * 256 + threadIdx.x;   // 262144
    int nl = gid & 15;
    int c  = (gid >> 4) & 3;
    int n8 = (gid >> 6) & 15;
    int r  = (gid >> 10) & 15;
    int k  = gid >> 14;
    int h = nl * 64 + (r >> 2) * 16 + n8;
    int w0 = (r & 3) * 256 + k * 16 + 4 * c;
    float4 v = *(const float4*)&x[h * 1024 + w0];
    const float* vp = (const float*)&v;
    float* dst = P2 + (((k * 16 + r) << 12) | (n8 << 8) | nl);
#pragma unroll
    for (int j = 0; j < 4; ++j)
        dst[(4 * c + j) << 4] = vp[j];
}

// ---- sq[k][n] (verified R15) ----
__global__ __launch_bounds__(256) void sq2_kernel(const float* __restrict__ P2,
                                                  float* __restrict__ sq) {
#pragma clang fp contract(off)
    int gid = blockIdx.x * 256 + threadIdx.x;   // 65536
    int n = gid & 4095;
    int k = gid >> 12;
    const float* p = P2 + ((k * 16) << 12) + n;
    float v0 = p[0];
    float acc = v0 * v0;
#pragma unroll
    for (int r = 1; r < 16; ++r) {
        float v = p[r << 12];
        float t = v * v;
        acc = acc + t;
    }
    sq[(k << 12) + n] = acc;
}

// ---- hybrid adjacency: a via VMEM, b via LDS ----
__global__ __launch_bounds__(256, 2) void adj3_kernel(const float* __restrict__ P2,
                                                      const float* __restrict__ sq,
                                                      float* __restrict__ A) {
#pragma clang fp contract(off)
    __shared__ float4 Sj[64 * 16];   // [kr][chunk]; logical chunk c at c^(kr&7); 16 KB

    // linear -> lower-triangle (bi >= bj)
    int t = blockIdx.x;
    int bi = (int)((sqrtf(8.0f * (float)t + 1.0f) - 1.0f) * 0.5f);
    while ((bi + 1) * (bi + 2) / 2 <= t) ++bi;
    while (bi * (bi + 1) / 2 > t) --bi;
    int bj = t - bi * (bi + 1) / 2;

    const int i0 = bi * BT;
    const int j0 = bj * BT;
    const int tid = threadIdx.x;
    const int tx = tid & 15;       // j-cols tx*4..+3
    const int ty = tid >> 4;       // i-rows ty*4..+3
    const int ia = i0 + 4 * ty;
    const int ja = j0 + 4 * tx;

    unsigned int bad = 0u;         // bit u*4+v => some d2 > 49

    for (int kp = 0; kp < 4; ++kp) {
        __syncthreads();
        // ---- stage j-tile slice (4 k) from P2: trivially coalesced ----
        {
            int kr = tid >> 2;                 // 0..63: kl = kr>>4, r = kr&15
            int q = tid & 3;
            int k = kp * 4 + (kr >> 4);
            int r = kr & 15;
            const float4* src = (const float4*)&P2[(((k << 4) | r) << 12) + j0] + (q << 2);
            float4* dst = &Sj[kr << 4];
            int f = kr & 7;
#pragma unroll
            for (int s0 = 0; s0 < 4; ++s0)
                dst[((q << 2) | s0) ^ f] = src[s0];
        }
        __syncthreads();
        // ---- compute: per k, a from global (1 line/wave-instr), b from LDS ----
#pragma unroll
        for (int kl = 0; kl < 4; ++kl) {
            int k = kp * 4 + kl;
            const float* baseA = P2 + (((size_t)k << 4) << 12) + ia;
            float d[4][4];
#pragma unroll
            for (int u = 0; u < 4; ++u)
#pragma unroll
                for (int v = 0; v < 4; ++v) d[u][v] = 0.0f;
#pragma unroll
            for (int r = 0; r < 16; ++r) {
                float4 a4 = *(const float4*)&baseA[r << 12];
                float4 b4 = Sj[(((kl << 4) | r) << 4) | (tx ^ (r & 7))];
                const float* ap = (const float*)&a4;
                const float* bp = (const float*)&b4;
#pragma unroll
                for (int u = 0; u < 4; ++u)
#pragma unroll
                    for (int v = 0; v < 4; ++v)
                        d[u][v] = fmaf(ap[u], bp[v], d[u][v]);
            }
            float4 si4 = *(const float4*)&sq[(k << 12) + ia];
            float4 sj4 = *(const float4*)&sq[(k << 12) + ja];
            const float* sip = (const float*)&si4;
            const float* sjp = (const float*)&sj4;
#pragma unroll
            for (int u = 0; u < 4; ++u)
#pragma unroll
                for (int v = 0; v < 4; ++v) {
                    float s = sip[u] + sjp[v];            // fl(si+sj)
                    float d2 = fmaf(-2.0f, d[u][v], s);   // fl(s-2G)
                    bad |= (d2 > 49.0f) ? (1u << (u * 4 + v)) : 0u;
                }
        }
    }

    // ---- stores: direct + mirrored (A exactly symmetric) ----
#pragma unroll
    for (int u = 0; u < 4; ++u) {
        float4 o;
        o.x = (bad >> (u * 4 + 0)) & 1u ? 0.0f : 1.0f;
        o.y = (bad >> (u * 4 + 1)) & 1u ? 0.0f : 1.0f;
        o.z = (bad >> (u * 4 + 2)) & 1u ? 0.0f : 1.0f;
        o.w = (bad >> (u * 4 + 3)) & 1u ? 0.0f : 1.0f;
        *(float4*)&A[(size_t)(i0 + ty * 4 + u) * NPATCH + j0 + tx * 4] = o;
    }
    if (bi != bj) {
#pragma unroll
        for (int v = 0; v < 4; ++v) {
            float4 o;
            o.x = (bad >> (0 * 4 + v)) & 1u ? 0.0f : 1.0f;
            o.y = (bad >> (1 * 4 + v)) & 1u ? 0.0f : 1.0f;
            o.z = (bad >> (2 * 4 + v)) & 1u ? 0.0f : 1.0f;
            o.w = (bad >> (3 * 4 + v)) & 1u ? 0.0f : 1.0f;
            *(float4*)&A[(size_t)(j0 + tx * 4 + v) * NPATCH + i0 + ty * 4] = o;
        }
    }
}

// ====================== R13 fallback (proven, ws-free) ======================

#define KC 2
#define NPH 8
#define RSTRIDE 9

__device__ __forceinline__ int swzrow(int row) {
    return ((row >> 2) + (row >> 5)) & 7;
}

__global__ __launch_bounds__(256, 3) void adj_kernel(const float* __restrict__ x,
                                                     float* __restrict__ A) {
#pragma clang fp contract(off)
    __shared__ float4 Si[BT * RSTRIDE];
    __shared__ float4 Sj[BT * RSTRIDE];
    __shared__ float sqs[2][KC][BT];

    int t = blockIdx.x;
    int bi = (int)((sqrtf(8.0f * (float)t + 1.0f) - 1.0f) * 0.5f);
    while ((bi + 1) * (bi + 2) / 2 <= t) ++bi;
    while (bi * (bi + 1) / 2 > t) --bi;
    int bj = t - bi * (bi + 1) / 2;

    const int i0 = bi * BT;
    const int j0 = bj * BT;
    const int tid = threadIdx.x;
    const int tx = tid & 15;
    const int ty = tid >> 4;
    const int swzA = (ty + (ty >> 3)) & 7;
    const int swzB = (tx + (tx >> 3)) & 7;

    float m[4][4];
#pragma unroll
    for (int u = 0; u < 4; ++u)
#pragma unroll
        for (int v = 0; v < 4; ++v) m[u][v] = -3.0e38f;

    for (int kp = 0; kp < NPH; ++kp) {
        __syncthreads();
#pragma unroll
        for (int l = 0; l < 4; ++l) {
            int gid = l * 256 + tid;
            int side = gid >> 9;
            int q = gid & 511;
            int kl = q & 1;
            int r = (q >> 1) & 15;
            int rl = q >> 5;
            int k = kp * KC + kl;
            int b = side ? bj : bi;
            int h = rl * 64 + (r >> 2) * 16 + (b >> 2);
            int w0 = (r & 3) * 256 + k * 16 + ((4 * b) & 15);
            float4 v = *(const float4*)&x[h * 1024 + w0];
            const float* vp = (const float*)&v;
            int c = (kl << 2) | (r >> 2);
            int e = r & 3;
            float* Sb = side ? (float*)Sj : (float*)Si;
#pragma unroll
            for (int dd = 0; dd < 4; ++dd) {
                int row = 16 * dd + rl;
                int ch = c ^ swzrow(row);
                Sb[(row * RSTRIDE + ch) * 4 + e] = vp[dd];
            }
        }
        __syncthreads();
        {
            int side = tid >> 7;
            int kl = (tid >> 6) & 1;
            int row = tid & 63;
            const float4* Sb = (side ? Sj : Si) + row * RSTRIDE;
            int swz = swzrow(row);
            float acc;
            {
                float4 v = Sb[(kl * 4) ^ swz];
                acc = v.x * v.x;
                float t1 = v.y * v.y; acc = acc + t1;
                float t2 = v.z * v.z; acc = acc + t2;
                float t3 = v.w * v.w; acc = acc + t3;
            }
#pragma unroll
            for (int rc = 1; rc < 4; ++rc) {
                float4 v = Sb[(kl * 4 + rc) ^ swz];
                float t0 = v.x * v.x; acc = acc + t0;
                float t1 = v.y * v.y; acc = acc + t1;
                float t2 = v.z * v.z; acc = acc + t2;
                float t3 = v.w * v.w; acc = acc + t3;
            }
            sqs[side][kl][row] = acc;
        }
        __syncthreads();
#pragma unroll
        for (int kl = 0; kl < KC; ++kl) {
            float d[4][4];
#pragma unroll
            for (int u = 0; u < 4; ++u)
#pragma unroll
                for (int v = 0; v < 4; ++v) d[u][v] = 0.0f;
#pragma unroll
            for (int rc = 0; rc < 4; ++rc) {
                int c = kl * 4 + rc;
                float4 a[4], b[4];
#pragma unroll
                for (int u = 0; u < 4; ++u)
                    a[u] = Si[(ty * 4 + u) * RSTRIDE + (c ^ swzA)];
#pragma unroll
                for (int v = 0; v < 4; ++v)
                    b[v] = Sj[(tx * 4 + v) * RSTRIDE + (c ^ swzB)];
#pragma unroll
                for (int u = 0; u < 4; ++u)
#pragma unroll
                    for (int v = 0; v < 4; ++v) {
                        d[u][v] = fmaf(a[u].x, b[v].x, d[u][v]);
                        d[u][v] = fmaf(a[u].y, b[v].y, d[u][v]);
                        d[u][v] = fmaf(a[u].z, b[v].z, d[u][v]);
                        d[u][v] = fmaf(a[u].w, b[v].w, d[u][v]);
                    }
            }
            float4 si4 = *(const float4*)&sqs[0][kl][ty * 4];
            float4 sj4 = *(const float4*)&sqs[1][kl][tx * 4];
            const float* sip = (const float*)&si4;
            const float* sjp = (const float*)&sj4;
#pragma unroll
            for (int u = 0; u < 4; ++u)
#pragma unroll
                for (int v = 0; v < 4; ++v) {
                    float s = sip[u] + sjp[v];
                    float d2 = fmaf(-2.0f, d[u][v], s);
                    m[u][v] = fmaxf(m[u][v], d2);
                }
        }
    }

#pragma unroll
    for (int u = 0; u < 4; ++u) {
        float4 o;
        o.x = (m[u][0] <= 49.0f) ? 1.0f : 0.0f;
        o.y = (m[u][1] <= 49.0f) ? 1.0f : 0.0f;
        o.z = (m[u][2] <= 49.0f) ? 1.0f : 0.0f;
        o.w = (m[u][3] <= 49.0f) ? 1.0f : 0.0f;
        *(float4*)&A[(size_t)(i0 + ty * 4 + u) * NPATCH + j0 + tx * 4] = o;
    }
    if (bi != bj) {
#pragma unroll
        for (int v = 0; v < 4; ++v) {
            float4 o;
            o.x = (m[0][v] <= 49.0f) ? 1.0f : 0.0f;
            o.y = (m[1][v] <= 49.0f) ? 1.0f : 0.0f;
            o.z = (m[2][v] <= 49.0f) ? 1.0f : 0.0f;
            o.w = (m[3][v] <= 49.0f) ? 1.0f : 0.0f;
            *(float4*)&A[(size_t)(j0 + tx * 4 + v) * NPATCH + i0 + ty * 4] = o;
        }
    }
}

extern "C" void kernel_launch(void* const* d_in, const int* in_sizes, int n_in,
                              void* d_out, int out_size, void* d_ws, size_t ws_size,
                              hipStream_t stream) {
    const float* x = (const float*)d_in[0];
    float* A = (float*)d_out;

    const int nblk = (NPATCH / BT) * (NPATCH / BT + 1) / 2;  // 2080
    const size_t need = (size_t)4 * 1024 * 1024 + 256 * 1024;

    if (ws_size >= need) {
        float* P2 = (float*)d_ws;                                    // 4 MB
        float* sq = (float*)((char*)d_ws + (size_t)4 * 1024 * 1024); // 256 KB
        transpose_kernel<<<1024, 256, 0, stream>>>(x, P2);
        sq2_kernel<<<256, 256, 0, stream>>>(P2, sq);
        adj3_kernel<<<nblk, 256, 0, stream>>>(P2, sq, A);
    } else {
        adj_kernel<<<nblk, 256, 0, stream>>>(x, A);
    }
}

// Round 17
// 167.250 us; speedup vs baseline: 1.3952x; 1.3025x over previous
//
#include <hip/hip_runtime.h>

// GraphConstruction: x[1,1024,1024] fp32 -> A[4096,4096] in {0,1} fp32.
// patches[n,r,k] = x[h,w], h = (n&15)*64 + (r>>2)*16 + (n>>8),
//                          w = (r&3)*256 + k*16 + ((n>>4)&15)
// LOCKED NUMERICS (R6..R16, absmax 0):
//   sq[n,k]: acc = p0^2; acc = acc + fl(p_r^2), r ascending (plain adds)
//   G: acc = fmaf(a_r, b_r, acc), r ascending
//   d2 = fmaf(-2,G,fl(si+sj));  all_k (d2 <= 49.0f);  A symmetric -> mirror.
// R17: R13's 4x4/64-reg LDS core (the only shape that keeps 8 waves/EU —
//   every >72-VGPR variant went latency-bound: R8/9/11/12/15/16), but staged
//   from pre-transposed P2[k][r][n] instead of x:
//   - staging = 4 coalesced float4 loads + 4 contiguous ds_write_b128/thread
//     (R13: 16 scattered b32 writes + ~100 VALU munge ops)
//   - LDS [side][kl][r][chunk]: a-reads broadcast conflict-FREE, b-reads
//     exactly 2-way (free, m136) — no swizzle needed
//   - sq from verified sq2 buffer via VMEM (drops the 3rd barrier + DS reads)
//   Compute core + per-cell numerics byte-identical to R13.

#define NPATCH 4096
#define BT 64

// ---- P2[k][r][n] transpose (verified R15/R16) ----
__global__ __launch_bounds__(256) void transpose_kernel(const float* __restrict__ x,
                                                        float* __restrict__ P2) {
    int gid = blockIdx.x * 256 + threadIdx.x;   // 262144
    int nl = gid & 15;
    int c  = (gid >> 4) & 3;
    int n8 = (gid >> 6) & 15;
    int r  = (gid >> 10) & 15;
    int k  = gid >> 14;
    int h = nl * 64 + (r >> 2) * 16 + n8;
    int w0 = (r & 3) * 256 + k * 16 + 4 * c;
    float4 v = *(const float4*)&x[h * 1024 + w0];
    const float* vp = (const float*)&v;
    float* dst = P2 + (((k * 16 + r) << 12) | (n8 << 8) | nl);
#pragma unroll
    for (int j = 0; j < 4; ++j)
        dst[(4 * c + j) << 4] = vp[j];
}

// ---- sq[k][n] (verified R15/R16) ----
__global__ __launch_bounds__(256) void sq2_kernel(const float* __restrict__ P2,
                                                  float* __restrict__ sq) {
#pragma clang fp contract(off)
    int gid = blockIdx.x * 256 + threadIdx.x;   // 65536
    int n = gid & 4095;
    int k = gid >> 12;
    const float* p = P2 + ((k * 16) << 12) + n;
    float v0 = p[0];
    float acc = v0 * v0;
#pragma unroll
    for (int r = 1; r < 16; ++r) {
        float v = p[r << 12];
        float t = v * v;
        acc = acc + t;
    }
    sq[(k << 12) + n] = acc;
}

// ---- adjacency: both tiles in LDS, staged from P2; R13 compute core ----
__global__ __launch_bounds__(256, 3) void adj4_kernel(const float* __restrict__ P2,
                                                      const float* __restrict__ sq,
                                                      float* __restrict__ A) {
#pragma clang fp contract(off)
    __shared__ float4 S[2][2][16][16];   // [side][kl][r][chunk] = 16 KB

    // linear -> lower-triangle (bi >= bj)
    int t = blockIdx.x;
    int bi = (int)((sqrtf(8.0f * (float)t + 1.0f) - 1.0f) * 0.5f);
    while ((bi + 1) * (bi + 2) / 2 <= t) ++bi;
    while (bi * (bi + 1) / 2 > t) --bi;
    int bj = t - bi * (bi + 1) / 2;

    const int i0 = bi * BT;
    const int j0 = bj * BT;
    const int tid = threadIdx.x;
    const int tx = tid & 15;       // j-cols tx*4..+3
    const int ty = tid >> 4;       // i-rows ty*4..+3
    const int ia = i0 + 4 * ty;
    const int ja = j0 + 4 * tx;

    unsigned int bad = 0u;         // bit u*4+v => some d2 > 49

    for (int kp = 0; kp < 8; ++kp) {
        __syncthreads();
        // ---- stage both tiles from P2: coalesced loads, contiguous b128 writes ----
#pragma unroll
        for (int l = 0; l < 4; ++l) {
            int gid = l * 256 + tid;           // side(1)|kl(1)|r(4)|c(4)
            int c = gid & 15;
            int r = (gid >> 4) & 15;
            int kl = (gid >> 8) & 1;
            int side = gid >> 9;
            int k = kp * 2 + kl;
            float4 v = *(const float4*)&P2[(((k << 4) | r) << 12) + (side ? j0 : i0) + 4 * c];
            S[side][kl][r][c] = v;
        }
        __syncthreads();
        // ---- compute: 4x4 cells, fmaf chains r ascending ----
#pragma unroll
        for (int kl = 0; kl < 2; ++kl) {
            int k = kp * 2 + kl;
            float d[4][4];
#pragma unroll
            for (int u = 0; u < 4; ++u)
#pragma unroll
                for (int v = 0; v < 4; ++v) d[u][v] = 0.0f;
#pragma unroll
            for (int r = 0; r < 16; ++r) {
                float4 a4 = S[0][kl][r][ty];   // broadcast: conflict-free
                float4 b4 = S[1][kl][r][tx];   // 16 distinct: 2-way, free
                const float* ap = (const float*)&a4;
                const float* bp = (const float*)&b4;
#pragma unroll
                for (int u = 0; u < 4; ++u)
#pragma unroll
                    for (int v = 0; v < 4; ++v)
                        d[u][v] = fmaf(ap[u], bp[v], d[u][v]);
            }
            float4 si4 = *(const float4*)&sq[(k << 12) + ia];
            float4 sj4 = *(const float4*)&sq[(k << 12) + ja];
            const float* sip = (const float*)&si4;
            const float* sjp = (const float*)&sj4;
#pragma unroll
            for (int u = 0; u < 4; ++u)
#pragma unroll
                for (int v = 0; v < 4; ++v) {
                    float s = sip[u] + sjp[v];            // fl(si+sj)
                    float d2 = fmaf(-2.0f, d[u][v], s);   // fl(s-2G)
                    bad |= (d2 > 49.0f) ? (1u << (u * 4 + v)) : 0u;
                }
        }
    }

    // ---- stores: direct + mirrored (A exactly symmetric) ----
#pragma unroll
    for (int u = 0; u < 4; ++u) {
        float4 o;
        o.x = (bad >> (u * 4 + 0)) & 1u ? 0.0f : 1.0f;
        o.y = (bad >> (u * 4 + 1)) & 1u ? 0.0f : 1.0f;
        o.z = (bad >> (u * 4 + 2)) & 1u ? 0.0f : 1.0f;
        o.w = (bad >> (u * 4 + 3)) & 1u ? 0.0f : 1.0f;
        *(float4*)&A[(size_t)(i0 + ty * 4 + u) * NPATCH + j0 + tx * 4] = o;
    }
    if (bi != bj) {
#pragma unroll
        for (int v = 0; v < 4; ++v) {
            float4 o;
            o.x = (bad >> (0 * 4 + v)) & 1u ? 0.0f : 1.0f;
            o.y = (bad >> (1 * 4 + v)) & 1u ? 0.0f : 1.0f;
            o.z = (bad >> (2 * 4 + v)) & 1u ? 0.0f : 1.0f;
            o.w = (bad >> (3 * 4 + v)) & 1u ? 0.0f : 1.0f;
            *(float4*)&A[(size_t)(j0 + tx * 4 + v) * NPATCH + i0 + ty * 4] = o;
        }
    }
}

// ====================== R13 fallback (proven, ws-free) ======================

#define KC 2
#define NPH 8
#define RSTRIDE 9

__device__ __forceinline__ int swzrow(int row) {
    return ((row >> 2) + (row >> 5)) & 7;
}

__global__ __launch_bounds__(256, 3) void adj_kernel(const float* __restrict__ x,
                                                     float* __restrict__ A) {
#pragma clang fp contract(off)
    __shared__ float4 Si[BT * RSTRIDE];
    __shared__ float4 Sj[BT * RSTRIDE];
    __shared__ float sqs[2][KC][BT];

    int t = blockIdx.x;
    int bi = (int)((sqrtf(8.0f * (float)t + 1.0f) - 1.0f) * 0.5f);
    while ((bi + 1) * (bi + 2) / 2 <= t) ++bi;
    while (bi * (bi + 1) / 2 > t) --bi;
    int bj = t - bi * (bi + 1) / 2;

    const int i0 = bi * BT;
    const int j0 = bj * BT;
    const int tid = threadIdx.x;
    const int tx = tid & 15;
    const int ty = tid >> 4;
    const int swzA = (ty + (ty >> 3)) & 7;
    const int swzB = (tx + (tx >> 3)) & 7;

    float m[4][4];
#pragma unroll
    for (int u = 0; u < 4; ++u)
#pragma unroll
        for (int v = 0; v < 4; ++v) m[u][v] = -3.0e38f;

    for (int kp = 0; kp < NPH; ++kp) {
        __syncthreads();
#pragma unroll
        for (int l = 0; l < 4; ++l) {
            int gid = l * 256 + tid;
            int side = gid >> 9;
            int q = gid & 511;
            int kl = q & 1;
            int r = (q >> 1) & 15;
            int rl = q >> 5;
            int k = kp * KC + kl;
            int b = side ? bj : bi;
            int h = rl * 64 + (r >> 2) * 16 + (b >> 2);
            int w0 = (r & 3) * 256 + k * 16 + ((4 * b) & 15);
            float4 v = *(const float4*)&x[h * 1024 + w0];
            const float* vp = (const float*)&v;
            int c = (kl << 2) | (r >> 2);
            int e = r & 3;
            float* Sb = side ? (float*)Sj : (float*)Si;
#pragma unroll
            for (int dd = 0; dd < 4; ++dd) {
                int row = 16 * dd + rl;
                int ch = c ^ swzrow(row);
                Sb[(row * RSTRIDE + ch) * 4 + e] = vp[dd];
            }
        }
        __syncthreads();
        {
            int side = tid >> 7;
            int kl = (tid >> 6) & 1;
            int row = tid & 63;
            const float4* Sb = (side ? Sj : Si) + row * RSTRIDE;
            int swz = swzrow(row);
            float acc;
            {
                float4 v = Sb[(kl * 4) ^ swz];
                acc = v.x * v.x;
                float t1 = v.y * v.y; acc = acc + t1;
                float t2 = v.z * v.z; acc = acc + t2;
                float t3 = v.w * v.w; acc = acc + t3;
            }
#pragma unroll
            for (int rc = 1; rc < 4; ++rc) {
                float4 v = Sb[(kl * 4 + rc) ^ swz];
                float t0 = v.x * v.x; acc = acc + t0;
                float t1 = v.y * v.y; acc = acc + t1;
                float t2 = v.z * v.z; acc = acc + t2;
                float t3 = v.w * v.w; acc = acc + t3;
            }
            sqs[side][kl][row] = acc;
        }
        __syncthreads();
#pragma unroll
        for (int kl = 0; kl < KC; ++kl) {
            float d[4][4];
#pragma unroll
            for (int u = 0; u < 4; ++u)
#pragma unroll
                for (int v = 0; v < 4; ++v) d[u][v] = 0.0f;
#pragma unroll
            for (int rc = 0; rc < 4; ++rc) {
                int c = kl * 4 + rc;
                float4 a[4], b[4];
#pragma unroll
                for (int u = 0; u < 4; ++u)
                    a[u] = Si[(ty * 4 + u) * RSTRIDE + (c ^ swzA)];
#pragma unroll
                for (int v = 0; v < 4; ++v)
                    b[v] = Sj[(tx * 4 + v) * RSTRIDE + (c ^ swzB)];
#pragma unroll
                for (int u = 0; u < 4; ++u)
#pragma unroll
                    for (int v = 0; v < 4; ++v) {
                        d[u][v] = fmaf(a[u].x, b[v].x, d[u][v]);
                        d[u][v] = fmaf(a[u].y, b[v].y, d[u][v]);
                        d[u][v] = fmaf(a[u].z, b[v].z, d[u][v]);
                        d[u][v] = fmaf(a[u].w, b[v].w, d[u][v]);
                    }
            }
            float4 si4 = *(const float4*)&sqs[0][kl][ty * 4];
            float4 sj4 = *(const float4*)&sqs[1][kl][tx * 4];
            const float* sip = (const float*)&si4;
            const float* sjp = (const float*)&sj4;
#pragma unroll
            for (int u = 0; u < 4; ++u)
#pragma unroll
                for (int v = 0; v < 4; ++v) {
                    float s = sip[u] + sjp[v];
                    float d2 = fmaf(-2.0f, d[u][v], s);
                    m[u][v] = fmaxf(m[u][v], d2);
                }
        }
    }

#pragma unroll
    for (int u = 0; u < 4; ++u) {
        float4 o;
        o.x = (m[u][0] <= 49.0f) ? 1.0f : 0.0f;
        o.y = (m[u][1] <= 49.0f) ? 1.0f : 0.0f;
        o.z = (m[u][2] <= 49.0f) ? 1.0f : 0.0f;
        o.w = (m[u][3] <= 49.0f) ? 1.0f : 0.0f;
        *(float4*)&A[(size_t)(i0 + ty * 4 + u) * NPATCH + j0 + tx * 4] = o;
    }
    if (bi != bj) {
#pragma unroll
        for (int v = 0; v < 4; ++v) {
            float4 o;
            o.x = (m[0][v] <= 49.0f) ? 1.0f : 0.0f;
            o.y = (m[1][v] <= 49.0f) ? 1.0f : 0.0f;
            o.z = (m[2][v] <= 49.0f) ? 1.0f : 0.0f;
            o.w = (m[3][v] <= 49.0f) ? 1.0f : 0.0f;
            *(float4*)&A[(size_t)(j0 + tx * 4 + v) * NPATCH + i0 + ty * 4] = o;
        }
    }
}

extern "C" void kernel_launch(void* const* d_in, const int* in_sizes, int n_in,
                              void* d_out, int out_size, void* d_ws, size_t ws_size,
                              hipStream_t stream) {
    const float* x = (const float*)d_in[0];
    float* A = (float*)d_out;

    const int nblk = (NPATCH / BT) * (NPATCH / BT + 1) / 2;  // 2080
    const size_t need = (size_t)4 * 1024 * 1024 + 256 * 1024;

    if (ws_size >= need) {
        float* P2 = (float*)d_ws;                                    // 4 MB
        float* sq = (float*)((char*)d_ws + (size_t)4 * 1024 * 1024); // 256 KB
        transpose_kernel<<<1024, 256, 0, stream>>>(x, P2);
        sq2_kernel<<<256, 256, 0, stream>>>(P2, sq);
        adj4_kernel<<<nblk, 256, 0, stream>>>(P2, sq, A);
    } else {
        adj_kernel<<<nblk, 256, 0, stream>>>(x, A);
    }
}